// Round 1
// baseline (107.260 us; speedup 1.0000x reference)
//
#include <hip/hip_runtime.h>
#include <math.h>

#define DIM 2048
#define NB 32
#define NK 256

typedef float vf4 __attribute__((ext_vector_type(4)));

// ---------------- Kernel A v3: Bsum[b,i] = sum_j |s[b,i] - s[b,j]| ----------------
// grid (16, 32), 128 threads; each thread owns ONE complete Bsum[i].
// The j-loop reads row[j] at a wave-UNIFORM address -> compiler emits scalar
// (s_load) or broadcast L1 loads; the 8 KiB row is fully cached, so there is
// no LDS staging, no j-split, hence NO memset and NO atomics (3 dispatches -> 2).
// Per thread: 512 iters x 8 VALU = 4096 wave-instrs -> same ~3.4 us VALU floor
// as before, minus the atomic merge and fill dispatch.
__global__ __launch_bounds__(128) void bsum_kernel(const float* __restrict__ scores,
                                                   float* __restrict__ bsum) {
    const int b = blockIdx.y;
    const int i = blockIdx.x * 128 + (int)threadIdx.x;
    const float* __restrict__ row = scores + b * DIM;
    const float xi = row[i];
    const vf4* __restrict__ r4 = (const vf4*)row;

    float a0 = 0.f, a1 = 0.f, a2 = 0.f, a3 = 0.f;
    #pragma unroll 8
    for (int j = 0; j < DIM / 4; ++j) {
        const vf4 xj = r4[j];          // uniform address: scalar/broadcast load
        a0 += fabsf(xi - xj.x);
        a1 += fabsf(xi - xj.y);
        a2 += fabsf(xi - xj.z);
        a3 += fabsf(xi - xj.w);
    }
    bsum[b * DIM + i] = (a0 + a1) + (a2 + a3);
}

// ---------------- Kernel B: row softmax over i for each (b,k) ----------------
// (unchanged from the 91.9 us version — keeps the experiment attribution clean)
// grid (NK/4, NB), 256 threads = 4 waves; each wave owns ONE k entirely:
// no barriers, no LDS, no cross-k register liveness. Pure 6-step shuffle
// butterflies. Plain (cached) float4 stores — nt regressed in round 4.
__global__ __launch_bounds__(256) void softmax_kernel(const float* __restrict__ scores,
                                                      const float* __restrict__ bsum,
                                                      float* __restrict__ out) {
    const int b = blockIdx.y;
    const int w = threadIdx.x >> 6;       // wave id within block
    const int t = threadIdx.x & 63;       // lane
    const int k = blockIdx.x * 4 + w;
    const float scale = (float)(DIM - 1 - 2 * k);  // 2047 - 2k

    const vf4* __restrict__ s4  = (const vf4*)(scores + b * DIM);
    const vf4* __restrict__ bs4 = (const vf4*)(bsum   + b * DIM);

    float e[32];
    #pragma unroll
    for (int q = 0; q < 8; ++q) {
        const vf4 sv = s4[t + 64 * q];    // 64 lanes x 16 B contiguous
        const vf4 bv = bs4[t + 64 * q];
        e[4 * q + 0] = fmaf(sv.x, scale, -bv.x);
        e[4 * q + 1] = fmaf(sv.y, scale, -bv.y);
        e[4 * q + 2] = fmaf(sv.z, scale, -bv.z);
        e[4 * q + 3] = fmaf(sv.w, scale, -bv.w);
    }

    // ---- wave max: 4 local chains then 6-step butterfly ----
    float m0 = e[0], m1 = e[1], m2 = e[2], m3 = e[3];
    #pragma unroll
    for (int j = 4; j < 32; j += 4) {
        m0 = fmaxf(m0, e[j + 0]);
        m1 = fmaxf(m1, e[j + 1]);
        m2 = fmaxf(m2, e[j + 2]);
        m3 = fmaxf(m3, e[j + 3]);
    }
    float m = fmaxf(fmaxf(m0, m1), fmaxf(m2, m3));
    #pragma unroll
    for (int off = 32; off > 0; off >>= 1) m = fmaxf(m, __shfl_xor(m, off, 64));

    // ---- exp + wave sum ----
    float s0 = 0.f, s1 = 0.f, s2 = 0.f, s3 = 0.f;
    #pragma unroll
    for (int j = 0; j < 32; j += 4) {
        e[j + 0] = __expf(e[j + 0] - m); s0 += e[j + 0];
        e[j + 1] = __expf(e[j + 1] - m); s1 += e[j + 1];
        e[j + 2] = __expf(e[j + 2] - m); s2 += e[j + 2];
        e[j + 3] = __expf(e[j + 3] - m); s3 += e[j + 3];
    }
    float s = (s0 + s1) + (s2 + s3);
    #pragma unroll
    for (int off = 32; off > 0; off >>= 1) s += __shfl_xor(s, off, 64);

    const float inv = 1.f / s;
    vf4* o4 = (vf4*)(out + ((size_t)(b * NK + k)) * DIM);
    #pragma unroll
    for (int q = 0; q < 8; ++q) {
        vf4 o;
        o.x = e[4 * q + 0] * inv;
        o.y = e[4 * q + 1] * inv;
        o.z = e[4 * q + 2] * inv;
        o.w = e[4 * q + 3] * inv;
        o4[t + 64 * q] = o;
    }
}

extern "C" void kernel_launch(void* const* d_in, const int* in_sizes, int n_in,
                              void* d_out, int out_size, void* d_ws, size_t ws_size,
                              hipStream_t stream) {
    const float* scores = (const float*)d_in[0];
    float* out  = (float*)d_out;
    float* bsum = (float*)d_ws;  // NB*DIM floats = 256 KiB, fully overwritten by bsum_kernel

    bsum_kernel<<<dim3(16, NB), 128, 0, stream>>>(scores, bsum);
    softmax_kernel<<<dim3(NK / 4, NB), 256, 0, stream>>>(scores, bsum, out);
}

// Round 2
// 93.093 us; speedup vs baseline: 1.1522x; 1.1522x over previous
//
#include <hip/hip_runtime.h>
#include <math.h>

#define DIM 2048
#define NB 32
#define NK 256

typedef float vf4 __attribute__((ext_vector_type(4)));

// ---------------- Kernel A v4: partial Bsum, LDS-staged, NO atomics ----------------
// Bsum[b,i] = sum_j |s[b,i] - s[b,j]|, computed as 2 disjoint j-halves.
// grid (8, 2, 32): x = i-chunk (256 i), y = j-half (1024 j), z = batch.
// 256 threads, 1 i per thread. j-half staged in LDS (4 KiB) via coalesced vf4
// loads; inner loop reads LDS vf4 broadcasts (wave-uniform -> conflict-free,
// in-order lgkmcnt pipelines under the VALU work — this is what the s_load
// version of round 1 lost). Each block writes a DISJOINT slice of
// bsum_part[y][b][i]: no memset, no atomics. 512 blocks -> 8 waves/CU.
// Chip-wide VALU floor: 32*2048^2*2 ops = 8192 SIMD-cyc ~= 3.4 us.
__global__ __launch_bounds__(256) void bsum_kernel(const float* __restrict__ scores,
                                                   float* __restrict__ bsum_part) {
    __shared__ vf4 srow[256];  // 1024 floats = 4 KiB
    const int b  = blockIdx.z;
    const int j0 = blockIdx.y * 1024;
    const int i  = blockIdx.x * 256 + (int)threadIdx.x;
    const float* __restrict__ row = scores + b * DIM;

    srow[threadIdx.x] = ((const vf4*)(row + j0))[threadIdx.x];
    const float xi = row[i];
    __syncthreads();

    float a0 = 0.f, a1 = 0.f, a2 = 0.f, a3 = 0.f;
    #pragma unroll 4
    for (int jj = 0; jj < 256; ++jj) {
        const vf4 xj = srow[jj];
        a0 += fabsf(xi - xj.x);
        a1 += fabsf(xi - xj.y);
        a2 += fabsf(xi - xj.z);
        a3 += fabsf(xi - xj.w);
    }
    bsum_part[(size_t)blockIdx.y * NB * DIM + b * DIM + i] = (a0 + a1) + (a2 + a3);
}

// ---------------- Kernel B: row softmax over i for each (b,k) ----------------
// grid (NK/4, NB), 256 threads = 4 waves; each wave owns ONE k entirely:
// no barriers, no LDS, no cross-k register liveness. Pure 6-step shuffle
// butterflies. The two bsum partials are summed here (L2-resident loads,
// folded into the existing fma chain) instead of via atomics in kernel A.
__global__ __launch_bounds__(256) void softmax_kernel(const float* __restrict__ scores,
                                                      const float* __restrict__ bsum_part,
                                                      float* __restrict__ out) {
    const int b = blockIdx.y;
    const int w = threadIdx.x >> 6;       // wave id within block
    const int t = threadIdx.x & 63;       // lane
    const int k = blockIdx.x * 4 + w;
    const float scale = (float)(DIM - 1 - 2 * k);  // 2047 - 2k

    const vf4* __restrict__ s4  = (const vf4*)(scores + b * DIM);
    const vf4* __restrict__ bp0 = (const vf4*)(bsum_part + b * DIM);
    const vf4* __restrict__ bp1 = (const vf4*)(bsum_part + (size_t)NB * DIM + b * DIM);

    float e[32];
    #pragma unroll
    for (int q = 0; q < 8; ++q) {
        const vf4 sv = s4[t + 64 * q];    // 64 lanes x 16 B contiguous
        const vf4 b0 = bp0[t + 64 * q];
        const vf4 b1 = bp1[t + 64 * q];
        e[4 * q + 0] = fmaf(sv.x, scale, -(b0.x + b1.x));
        e[4 * q + 1] = fmaf(sv.y, scale, -(b0.y + b1.y));
        e[4 * q + 2] = fmaf(sv.z, scale, -(b0.z + b1.z));
        e[4 * q + 3] = fmaf(sv.w, scale, -(b0.w + b1.w));
    }

    // ---- wave max: 4 local chains then 6-step butterfly ----
    float m0 = e[0], m1 = e[1], m2 = e[2], m3 = e[3];
    #pragma unroll
    for (int j = 4; j < 32; j += 4) {
        m0 = fmaxf(m0, e[j + 0]);
        m1 = fmaxf(m1, e[j + 1]);
        m2 = fmaxf(m2, e[j + 2]);
        m3 = fmaxf(m3, e[j + 3]);
    }
    float m = fmaxf(fmaxf(m0, m1), fmaxf(m2, m3));
    #pragma unroll
    for (int off = 32; off > 0; off >>= 1) m = fmaxf(m, __shfl_xor(m, off, 64));

    // ---- exp + wave sum ----
    float s0 = 0.f, s1 = 0.f, s2 = 0.f, s3 = 0.f;
    #pragma unroll
    for (int j = 0; j < 32; j += 4) {
        e[j + 0] = __expf(e[j + 0] - m); s0 += e[j + 0];
        e[j + 1] = __expf(e[j + 1] - m); s1 += e[j + 1];
        e[j + 2] = __expf(e[j + 2] - m); s2 += e[j + 2];
        e[j + 3] = __expf(e[j + 3] - m); s3 += e[j + 3];
    }
    float s = (s0 + s1) + (s2 + s3);
    #pragma unroll
    for (int off = 32; off > 0; off >>= 1) s += __shfl_xor(s, off, 64);

    const float inv = 1.f / s;
    vf4* o4 = (vf4*)(out + ((size_t)(b * NK + k)) * DIM);
    #pragma unroll
    for (int q = 0; q < 8; ++q) {
        vf4 o;
        o.x = e[4 * q + 0] * inv;
        o.y = e[4 * q + 1] * inv;
        o.z = e[4 * q + 2] * inv;
        o.w = e[4 * q + 3] * inv;
        o4[t + 64 * q] = o;
    }
}

extern "C" void kernel_launch(void* const* d_in, const int* in_sizes, int n_in,
                              void* d_out, int out_size, void* d_ws, size_t ws_size,
                              hipStream_t stream) {
    const float* scores = (const float*)d_in[0];
    float* out  = (float*)d_out;
    float* bsum_part = (float*)d_ws;  // 2 * NB * DIM floats = 512 KiB, fully overwritten

    bsum_kernel<<<dim3(8, 2, NB), 256, 0, stream>>>(scores, bsum_part);
    softmax_kernel<<<dim3(NK / 4, NB), 256, 0, stream>>>(scores, bsum_part, out);
}